// Round 7
// baseline (134.790 us; speedup 1.0000x reference)
//
#include <hip/hip_runtime.h>

// Shapes: B=4, C=256, H=W=64, HW=4096, Co=256, offC=18, KK=9, K-dim = 9*256 = 2304
#define HWP 4096
#define NPIX 4194304   // B*256*4096
#define KDIM 2304

typedef __attribute__((ext_vector_type(4))) float f32x4;
typedef __attribute__((ext_vector_type(4))) int   i32x4;
typedef __attribute__((ext_vector_type(8))) short short8;
typedef __attribute__((ext_vector_type(4))) unsigned short bf16x4;
typedef __attribute__((ext_vector_type(4))) unsigned short u16x4;
typedef __attribute__((ext_vector_type(2))) unsigned int u32x2;

__device__ __forceinline__ unsigned short bf16_rne(float f) {
    unsigned int u = __builtin_bit_cast(unsigned int, f);
    u += 0x7FFFu + ((u >> 16) & 1u);
    return (unsigned short)(u >> 16);
}

__device__ __forceinline__ float bf2f(unsigned short u) {
    return __builtin_bit_cast(float, (unsigned int)u << 16);
}

__device__ __forceinline__ float u2f_lo(unsigned int u) {
    return __builtin_bit_cast(float, u << 16);
}

__device__ __forceinline__ float u2f_hi(unsigned int u) {
    return __builtin_bit_cast(float, u & 0xFFFF0000u);
}

__device__ __forceinline__ unsigned int cvt_pk_bf16(float lo, float hi) {
    unsigned int r;
    asm("v_cvt_pk_bf16_f32 %0, %1, %2" : "=v"(r) : "v"(lo), "v"(hi));
    return r;
}

__device__ __forceinline__ void gload_lds16(const void* g, void* l) {
    __builtin_amdgcn_global_load_lds((const __attribute__((address_space(1))) void*)g,
                                     (__attribute__((address_space(3))) void*)l, 16, 0, 0);
}

// ---- non-temporal helpers: keep zero-reuse streams out of L2 ----
__device__ __forceinline__ void ntst_f(float* p, float v) {
    __builtin_nontemporal_store(v, p);
}
__device__ __forceinline__ void ntst_us(unsigned short* p, unsigned short v) {
    __builtin_nontemporal_store(v, p);
}
__device__ __forceinline__ void ntst_u2(unsigned short* p, uint2 v) {
    u32x2 w; w[0] = v.x; w[1] = v.y;
    __builtin_nontemporal_store(w, reinterpret_cast<u32x2*>(p));
}
__device__ __forceinline__ void ntst_b4(unsigned short* p, bf16x4 v) {
    __builtin_nontemporal_store(v, reinterpret_cast<bf16x4*>(p));
}
__device__ __forceinline__ f32x4 ntld_f4(const float* p) {
    return __builtin_nontemporal_load(reinterpret_cast<const f32x4*>(p));
}
__device__ __forceinline__ u16x4 ntld_u4(const unsigned short* p) {
    return __builtin_nontemporal_load(reinterpret_cast<const u16x4*>(p));
}

// ============ merged prep: fbt (blocks 0..1023) + weights (blocks 1024..6719) ============
// w2A is FRAGMENT-MAJOR for direct global->register MFMA loads:
// addr = ((((cg*9 + tap)*8 + s)*4 + fr)*64 + l)*8 + e   (shorts)
// value = bf16(tw[o][ci][tap])  with  o = cg*64 + fr*16 + (l&15),  ci = s*32 + (l>>4)*8 + e
__global__ void prep_all_kernel(const float* __restrict__ x, unsigned short* __restrict__ fbt,
                                const float* __restrict__ dw0, const float* __restrict__ dw1,
                                const float* __restrict__ tw0, const float* __restrict__ tw1,
                                const float* __restrict__ ow0, const float* __restrict__ ow1,
                                unsigned short* __restrict__ w1b2,
                                unsigned short* __restrict__ w2A,
                                unsigned short* __restrict__ w2o) {
    __shared__ float T[64][65];
    int b = blockIdx.x;
    int t = threadIdx.x;
    if (b < 1024) {
        // fbt[b][pix][ci] = bf16(feat[b][ci][pix])  -- vectorized transpose:
        // read float4 (1 KB/wave-instr), write bf16x4 nt (512 B/wave-instr).
        int pt = b & 63, ct = (b >> 6) & 3, bb = b >> 8;
        int lane = t & 63;
        int w = t >> 6;          // wave 0..3
        int c0 = ct * 64, p0 = pt * 64;
        const float* xb = x + (size_t)(bb * 256 + c0) * HWP + p0;
#pragma unroll
        for (int j = 0; j < 4; ++j) {
            int ci = w * 16 + j * 4 + (lane >> 4);
            int px = (lane & 15) * 4;
            float4 v = *reinterpret_cast<const float4*>(xb + (size_t)ci * HWP + px);
            T[ci][px]     = v.x;
            T[ci][px + 1] = v.y;
            T[ci][px + 2] = v.z;
            T[ci][px + 3] = v.w;
        }
        __syncthreads();
        unsigned short* ob = fbt + ((size_t)bb * HWP + p0) * 256 + c0;
#pragma unroll
        for (int j = 0; j < 4; ++j) {
            int px  = w * 16 + j * 4 + (lane >> 4);
            int ci4 = (lane & 15) * 4;
            bf16x4 o4;
            o4[0] = bf16_rne(T[ci4 + 0][px]);
            o4[1] = bf16_rne(T[ci4 + 1][px]);
            o4[2] = bf16_rne(T[ci4 + 2][px]);
            o4[3] = bf16_rne(T[ci4 + 3][px]);
            ntst_b4(ob + (size_t)px * 256 + ci4, o4);
        }
        return;
    }
    int idx = (b - 1024) * 256 + t;   // up to 5696*256
    if (idx < 131072) {
        int br = idx >> 16;
        int i  = idx & 65535;
        const float* dw = br ? dw1 : dw0;
        ntst_us(&w1b2[idx], bf16_rne(dw[i]));
    } else if (idx < 131072 + 1179648) {
        int j = idx - 131072;
        int br = j >= 589824;
        int i  = br ? j - 589824 : j;
        const float* tw = br ? tw1 : tw0;
        int cg = i / 147456;            // 147456 = 9*8*4*64*8
        int r  = i - cg * 147456;
        int tap = r >> 14;              // / 16384
        int r2 = r & 16383;
        int s  = r2 >> 11;
        int fr = (r2 >> 9) & 3;
        int l  = (r2 >> 3) & 63;
        int e  = r2 & 7;
        int o  = cg * 64 + fr * 16 + (l & 15);
        int ci = s * 32 + ((l >> 4) << 3) + e;
        ntst_us(&w2A[j], bf16_rne(tw[(o * 256 + ci) * 9 + tap]));
    } else {
        int j = idx - 131072 - 1179648;   // < 147456
        int br = j >= 73728;
        int i  = br ? j - 73728 : j;
        const float* ow = br ? ow1 : ow0;
        int m = i / 2304;
        int k = i - m * 2304;
        int tap = k >> 8;
        int ci  = k & 255;
        ntst_us(&w2o[j], (m < 18) ? bf16_rne(ow[(m * 256 + ci) * 9 + tap]) : (unsigned short)0);
    }
}

// ---------------- tier-B small preps ----------------
__global__ void prep_w2_kernel(const float* __restrict__ tw0, const float* __restrict__ tw1,
                               unsigned short* __restrict__ w2) {
    int idx = blockIdx.x * 256 + threadIdx.x;
    int br = idx >= 589824;
    int i  = br ? idx - 589824 : idx;
    const float* tw = br ? tw1 : tw0;
    int ci = i & 255;
    int r  = i >> 8;
    int tap = r % 9;
    int o   = r / 9;
    w2[idx] = bf16_rne(tw[(o * 256 + ci) * 9 + tap]);
}

__global__ void prep_ow2_kernel(const float* __restrict__ ow0, const float* __restrict__ ow1,
                                float* __restrict__ owt) {
    int idx = blockIdx.x * 256 + threadIdx.x;
    int br = idx >= 41472;
    int i  = br ? idx - 41472 : idx;
    const float* ow = br ? ow1 : ow0;
    int co = i % 18;
    int r  = i / 18;
    int k  = r % 9;
    int ci = r / 9;
    owt[idx] = ow[(co * 256 + ci) * 9 + k];
}

__global__ void prep_w12_kernel(const float* __restrict__ dw0, const float* __restrict__ dw1,
                                unsigned short* __restrict__ w1b) {
    int idx = blockIdx.x * 256 + threadIdx.x;
    int br = idx >> 16;
    int i  = idx & 65535;
    const float* dw = br ? dw1 : dw0;
    w1b[idx] = bf16_rne(dw[i]);
}

__global__ void prep_fb16_kernel(const float* __restrict__ x, unsigned short* __restrict__ fbt) {
    __shared__ float T[64][65];
    int pt = blockIdx.x;
    int ct = blockIdx.y;
    int bb = blockIdx.z;
    int t = threadIdx.x;
    int lane = t & 63;
    int r = t >> 6;
    int c0 = ct * 64, p0 = pt * 64;
    const float* xb = x + (size_t)(bb * 256 + c0) * HWP + p0;
#pragma unroll
    for (int rr = 0; rr < 16; ++rr) {
        int ci = r * 16 + rr;
        T[ci][lane] = xb[(size_t)ci * HWP + lane];
    }
    __syncthreads();
    unsigned short* ob = fbt + ((size_t)bb * HWP + p0) * 256 + c0;
#pragma unroll
    for (int rr = 0; rr < 16; ++rr) {
        int px = r * 16 + rr;
        ob[(size_t)px * 256 + lane] = bf16_rne(T[lane][px]);
    }
}

// ------- conv1x1 MFMA GEMM; z = br*4+bb; writes ht (bf16) and optionally h (fp32) -------
__launch_bounds__(256)
__global__ void gemm1x1_kernel(const unsigned short* __restrict__ w1b2,
                               const unsigned short* __restrict__ fbt,
                               const float* __restrict__ db0, const float* __restrict__ db1,
                               float* __restrict__ h2, unsigned short* __restrict__ ht2,
                               int write_h) {
    __shared__ unsigned short As[128 * 64];
    __shared__ unsigned short Bs[64 * 64];
    int pt = blockIdx.x;
    int ot = blockIdx.y;
    int z  = blockIdx.z;
    int bb = z & 3;
    int br = z >> 2;
    const unsigned short* w1b = w1b2 + (size_t)br * 65536;
    const float* db = br ? db1 : db0;
    int t  = threadIdx.x;
    int l  = t & 63;
    int w  = t >> 6;
    int wr = w >> 1, wc = w & 1;
    int o0 = ot * 128, p0 = pt * 64;
    const unsigned short* fb = fbt + (size_t)bb * HWP * 256;
    f32x4 acc[4][2];
#pragma unroll
    for (int i = 0; i < 4; ++i)
#pragma unroll
        for (int j = 0; j < 2; ++j) acc[i][j] = (f32x4){0.f, 0.f, 0.f, 0.f};

    for (int ks = 0; ks < 4; ++ks) {
        int k0 = ks * 64;
#pragma unroll
        for (int rA = 0; rA < 4; ++rA) {
            int s = rA * 256 + t;
            int row = s >> 3, cg = (s & 7) ^ (row & 7);
            gload_lds16(w1b + (size_t)(o0 + row) * 256 + k0 + cg * 8, As + s * 8);
        }
#pragma unroll
        for (int rB = 0; rB < 2; ++rB) {
            int s = rB * 256 + t;
            int row = s >> 3, cg = (s & 7) ^ (row & 7);
            gload_lds16(fb + (size_t)(p0 + row) * 256 + k0 + cg * 8, Bs + s * 8);
        }
        __syncthreads();
#pragma unroll
        for (int half = 0; half < 2; ++half) {
            short8 a[4], b[2];
#pragma unroll
            for (int fr = 0; fr < 4; ++fr) {
                int row = wr * 64 + fr * 16 + (l & 15);
                int oct = half * 4 + (l >> 4);
                a[fr] = *reinterpret_cast<const short8*>(As + row * 64 + ((oct ^ (row & 7)) * 8));
            }
#pragma unroll
            for (int fc = 0; fc < 2; ++fc) {
                int row = wc * 32 + fc * 16 + (l & 15);
                int oct = half * 4 + (l >> 4);
                b[fc] = *reinterpret_cast<const short8*>(Bs + row * 64 + ((oct ^ (row & 7)) * 8));
            }
#pragma unroll
            for (int fr = 0; fr < 4; ++fr)
#pragma unroll
                for (int fc = 0; fc < 2; ++fc)
                    acc[fr][fc] = __builtin_amdgcn_mfma_f32_16x16x32_bf16(a[fr], b[fc], acc[fr][fc], 0, 0, 0);
        }
        __syncthreads();
    }

    float* hb = h2 + (size_t)br * NPIX + (size_t)bb * 256 * HWP;
    unsigned short* htb = ht2 + (size_t)br * NPIX + (size_t)bb * HWP * 256;
#pragma unroll
    for (int fr = 0; fr < 4; ++fr) {
        int o = o0 + wr * 64 + fr * 16 + ((l >> 4) << 2);
#pragma unroll
        for (int fc = 0; fc < 2; ++fc) {
            int p = p0 + wc * 32 + fc * 16 + (l & 15);
            f32x4 v;
#pragma unroll
            for (int reg = 0; reg < 4; ++reg) {
                v[reg] = acc[fr][fc][reg] + db[o + reg];
                if (write_h) ntst_f(&hb[(size_t)(o + reg) * HWP + p], v[reg]);
            }
            uint2 pk;
            pk.x = cvt_pk_bf16(v[0], v[1]);
            pk.y = cvt_pk_bf16(v[2], v[3]);
            ntst_u2(htb + (size_t)p * 256 + o, pk);
        }
    }
}

// ---------------- offset conv3x3 as MFMA mini-GEMM (4-wave K-split) ----------------
// Epilogue emits per-(px,tap) sampling descriptors:
// 4 f32 bilinear weights (validity folded) + 4 packed u16 clamped pixel indices.
__launch_bounds__(256)
__global__ void off_mfma_kernel(const unsigned short* __restrict__ w2o,
                                const unsigned short* __restrict__ ht2,
                                const float* __restrict__ ob0, const float* __restrict__ ob1,
                                float* __restrict__ dwq, unsigned short* __restrict__ dcq) {
    __shared__ float red[4][1152];   // 18 KB
    int id = blockIdx.x;          // 512 = br*256 + bb*64 + y
    int br = id >> 8;
    int bb = (id >> 6) & 3;
    int y  = id & 63;
    const unsigned short* wA = w2o + (size_t)br * 73728;
    const unsigned short* htb = ht2 + (size_t)br * NPIX + (size_t)bb * HWP * 256;
    const float* ob = br ? ob1 : ob0;
    int t = threadIdx.x;
    int l = t & 63;
    int w = t >> 6;               // wave 0..3
    short8 zero = {};
    f32x4 acc[2][4];
#pragma unroll
    for (int i = 0; i < 2; ++i)
#pragma unroll
        for (int j = 0; j < 4; ++j) acc[i][j] = (f32x4){0.f, 0.f, 0.f, 0.f};

    for (int tap = 0; tap < 9; ++tap) {
        int ky = tap / 3, kx = tap % 3;
        int yy = y + ky - 1;
        bool vy = (yy >= 0) && (yy < 64);
        int cyy = min(max(yy, 0), 63);
#pragma unroll
        for (int sh = 0; sh < 2; ++sh) {
            int s = w * 2 + sh;   // wave-private K quarter
            short8 a[2], b[4];
#pragma unroll
            for (int fr = 0; fr < 2; ++fr)
                a[fr] = *reinterpret_cast<const short8*>(
                    wA + (size_t)(fr * 16 + (l & 15)) * KDIM + tap * 256 + s * 32 + ((l >> 4) << 3));
#pragma unroll
            for (int fc = 0; fc < 4; ++fc) {
                int px = fc * 16 + (l & 15);
                int xx = px + kx - 1;
                bool v = vy && (xx >= 0) && (xx < 64);
                int cxx = min(max(xx, 0), 63);
                short8 bv = *reinterpret_cast<const short8*>(
                    htb + (size_t)(cyy * 64 + cxx) * 256 + s * 32 + ((l >> 4) << 3));
                b[fc] = v ? bv : zero;
            }
#pragma unroll
            for (int fr = 0; fr < 2; ++fr)
#pragma unroll
                for (int fc = 0; fc < 4; ++fc)
                    acc[fr][fc] = __builtin_amdgcn_mfma_f32_16x16x32_bf16(a[fr], b[fc], acc[fr][fc], 0, 0, 0);
        }
    }

    // partials -> LDS, reduce over 4 waves
#pragma unroll
    for (int fr = 0; fr < 2; ++fr)
#pragma unroll
        for (int fc = 0; fc < 4; ++fc) {
            int px = fc * 16 + (l & 15);
#pragma unroll
            for (int reg = 0; reg < 4; ++reg) {
                int co = fr * 16 + ((l >> 4) << 2) + reg;
                if (co < 18) red[w][co * 64 + px] = acc[fr][fc][reg];
            }
        }
    __syncthreads();

    // descriptor epilogue: 64 px x 9 taps for this (br,bb,y)
    size_t dbase = ((size_t)(br * 4 + bb) * 9) * 4096 + (size_t)(y * 64);
    for (int e = t; e < 576; e += 256) {
        int tap = e >> 6, px = e & 63;
        int c0 = 2 * tap, c1 = 2 * tap + 1;
        float dy = ob[c0] + red[0][c0 * 64 + px] + red[1][c0 * 64 + px]
                          + red[2][c0 * 64 + px] + red[3][c0 * 64 + px];
        float dx = ob[c1] + red[0][c1 * 64 + px] + red[1][c1 * 64 + px]
                          + red[2][c1 * 64 + px] + red[3][c1 * 64 + px];
        int ky = tap / 3, kx = tap % 3;
        float sy = (float)(y - 1 + ky) + dy;
        float sx = (float)(px - 1 + kx) + dx;
        float y0f = floorf(sy), x0f = floorf(sx);
        float ty = sy - y0f, tx = sx - x0f;
        int iy0 = (int)y0f, ix0 = (int)x0f;
        int iy1 = iy0 + 1, ix1 = ix0 + 1;
        bool vy0 = (iy0 >= 0) & (iy0 < 64);
        bool vy1 = (iy1 >= 0) & (iy1 < 64);
        bool vx0 = (ix0 >= 0) & (ix0 < 64);
        bool vx1 = (ix1 >= 0) & (ix1 < 64);
        int cy0 = min(max(iy0, 0), 63), cy1 = min(max(iy1, 0), 63);
        int cx0 = min(max(ix0, 0), 63), cx1 = min(max(ix1, 0), 63);
        f32x4 ww;
        ww[0] = (1.f - ty) * (1.f - tx) * ((vy0 & vx0) ? 1.f : 0.f);
        ww[1] = (1.f - ty) * tx * ((vy0 & vx1) ? 1.f : 0.f);
        ww[2] = ty * (1.f - tx) * ((vy1 & vx0) ? 1.f : 0.f);
        ww[3] = ty * tx * ((vy1 & vx1) ? 1.f : 0.f);
        u16x4 pc;
        pc[0] = (unsigned short)(cy0 * 64 + cx0);
        pc[1] = (unsigned short)(cy0 * 64 + cx1);
        pc[2] = (unsigned short)(cy1 * 64 + cx0);
        pc[3] = (unsigned short)(cy1 * 64 + cx1);
        size_t di = dbase + (size_t)tap * 4096 + px;
        __builtin_nontemporal_store(ww, reinterpret_cast<f32x4*>(dwq + di * 4));
        __builtin_nontemporal_store(pc, reinterpret_cast<u16x4*>(dcq + di * 4));
    }
}

// ---------------- tier-B offset conv ----------------
__global__ void off_conv_part_kernel(const float* __restrict__ h2, const float* __restrict__ owt2,
                                     float* __restrict__ part2) {
    int y  = blockIdx.x & 63;
    int bb = blockIdx.x >> 6;
    int c  = blockIdx.y;
    int br = blockIdx.z;
    const float* h = h2 + (size_t)br * NPIX;
    const float* owt = owt2 + (size_t)br * 41472;
    float* part = part2 + (size_t)br * 2359296;
    int t  = threadIdx.x;
    int x  = t & 63;
    int wv = __builtin_amdgcn_readfirstlane(t >> 6);
    int  toff[9];
    bool tval[9];
#pragma unroll
    for (int ky = 0; ky < 3; ++ky) {
        int yy = y + ky - 1;
        bool vy = (yy >= 0) && (yy < 64);
        int cyy = min(max(yy, 0), 63);
#pragma unroll
        for (int kx = 0; kx < 3; ++kx) {
            int xx = x + kx - 1;
            tval[ky * 3 + kx] = vy && (xx >= 0) && (xx < 64);
            toff[ky * 3 + kx] = cyy * 64 + min(max(xx, 0), 63);
        }
    }
    float acc[18];
#pragma unroll
    for (int co = 0; co < 18; ++co) acc[co] = 0.f;
    int ci0 = c * 32 + wv * 8;
    const float* hb = h + (size_t)(bb * 256 + ci0) * HWP;
#pragma unroll
    for (int i = 0; i < 8; ++i) {
        const float* hc = hb + i * HWP;
        const float* wci = owt + (size_t)(ci0 + i) * 162;
#pragma unroll
        for (int k = 0; k < 9; ++k) {
            float hv = hc[toff[k]];
            hv = tval[k] ? hv : 0.f;
            const float* wk = wci + k * 18;
#pragma unroll
            for (int co = 0; co < 18; ++co)
                acc[co] = fmaf(wk[co], hv, acc[co]);
        }
    }
    __shared__ float red[4][18][64];
    int wvl = t >> 6;
#pragma unroll
    for (int co = 0; co < 18; ++co) red[wvl][co][x] = acc[co];
    __syncthreads();
    if (wvl == 0) {
#pragma unroll
        for (int co = 0; co < 18; ++co) {
            float s = red[0][co][x] + red[1][co][x] + red[2][co][x] + red[3][co][x];
            part[(size_t)c * 294912 + ((bb * 18 + co) << 12) + (y << 6) + x] = s;
        }
    }
}

__global__ void off_reduce2_kernel(const float* __restrict__ part2,
                                   const float* __restrict__ ob0, const float* __restrict__ ob1,
                                   float* __restrict__ off2) {
    int idx = blockIdx.x * 256 + threadIdx.x;
    int br = idx >= 294912;
    int i  = br ? idx - 294912 : idx;
    const float* part = part2 + (size_t)br * 2359296;
    const float* b = br ? ob1 : ob0;
    int co = (i >> 12) % 18;
    float s = b[co];
#pragma unroll
    for (int c = 0; c < 8; ++c) s += part[(size_t)c * 294912 + i];
    off2[idx] = s;
}

// ---------------- FUSED deform sample + GEMM + bias + ReLU ----------------
// v12 = v7 structure + nt hints: 4 waves x (64 out-ch x 64 px),
// A direct global->reg (fragment-major w2A), Bs double-buffered, ONE barrier per tap.
// Descriptor reads nt (zero reuse), output stores nt (write-once) -> L2 kept for ht+A.
__launch_bounds__(256, 2)
__global__ void dgemm_fused_kernel(const unsigned short* __restrict__ w2b,
                                   const unsigned short* __restrict__ ht2,
                                   const float* __restrict__ dwq,
                                   const unsigned short* __restrict__ dcq,
                                   const float* __restrict__ tb0,
                                   const float* __restrict__ tb1,
                                   float* __restrict__ out) {
    __shared__ unsigned short Bs[2][64 * 256];   // 64 KB
    int id = blockIdx.x;
    int sw = (id & 7) * 64 + (id >> 3);        // XCD swizzle
    int br = sw >> 8;
    int mt = sw & 255;
    int bb = mt >> 6;
    int y  = mt & 63;
    const unsigned short* w2f = w2b + (size_t)br * 589824;
    const unsigned short* htb = ht2 + (size_t)br * NPIX + (size_t)bb * HWP * 256;
    const float* bias = br ? tb1 : tb0;
    size_t dbase = ((size_t)(br * 4 + bb) * 9) * 4096 + (size_t)(y * 64);
    int t = threadIdx.x;
    int l = t & 63;
    int w = t >> 6;
    int wvu = __builtin_amdgcn_readfirstlane(w);
    int le = l << 2;

    f32x4 acc[4][4];
#pragma unroll
    for (int i = 0; i < 4; ++i)
#pragma unroll
        for (int j = 0; j < 4; ++j) acc[i][j] = (f32x4){0.f, 0.f, 0.f, 0.f};

// stage 16 px of tap TAPV into WB (per-wave px block)
#define STAGE_B(TAPV, WB)                                                          \
    do {                                                                           \
        const float* dwt = dwq + (dbase + (size_t)(TAPV) * 4096) * 4;              \
        const unsigned short* dct = dcq + (dbase + (size_t)(TAPV) * 4096) * 4;     \
        _Pragma("unroll")                                                          \
        for (int i_ = 0; i_ < 16; ++i_) {                                          \
            int px = wvu * 16 + i_;                                                \
            f32x4 ww = ntld_f4(dwt + (size_t)px * 4);                              \
            u16x4 pc = ntld_u4(dct + (size_t)px * 4);                              \
            int b00 = ((int)pc[0] << 8) + le;                                      \
            int b01 = ((int)pc[1] << 8) + le;                                      \
            int b10 = ((int)pc[2] << 8) + le;                                      \
            int b11 = ((int)pc[3] << 8) + le;                                      \
            uint2 u00 = *reinterpret_cast<const uint2*>(htb + b00);                \
            uint2 u01 = *reinterpret_cast<const uint2*>(htb + b01);                \
            uint2 u10 = *reinterpret_cast<const uint2*>(htb + b10);                \
            uint2 u11 = *reinterpret_cast<const uint2*>(htb + b11);                \
            float s0 = fmaf(ww[0], u2f_lo(u00.x),                                  \
                       fmaf(ww[1], u2f_lo(u01.x),                                  \
                       fmaf(ww[2], u2f_lo(u10.x), ww[3] * u2f_lo(u11.x))));        \
            float s1 = fmaf(ww[0], u2f_hi(u00.x),                                  \
                       fmaf(ww[1], u2f_hi(u01.x),                                  \
                       fmaf(ww[2], u2f_hi(u10.x), ww[3] * u2f_hi(u11.x))));        \
            float s2 = fmaf(ww[0], u2f_lo(u00.y),                                  \
                       fmaf(ww[1], u2f_lo(u01.y),                                  \
                       fmaf(ww[2], u2f_lo(u10.y), ww[3] * u2f_lo(u11.y))));        \
            float s3 = fmaf(ww[0], u2f_hi(u00.y),                                  \
                       fmaf(ww[1], u2f_hi(u01.y),                                  \
                       fmaf(ww[2], u2f_hi(u10.y), ww[3] * u2f_hi(u11.y))));        \
            uint2 pk;                                                              \
            pk.x = cvt_pk_bf16(s0, s1);                                            \
            pk.y = cvt_pk_bf16(s2, s3);                                            \
            int g = l >> 1, sub = l & 1;                                           \
            *reinterpret_cast<uint2*>((WB) + px * 256 +                            \
                (((g ^ (px & 7)) << 3) | (sub << 2))) = pk;                        \
        }                                                                          \
    } while (0)

// compute tap TAPV from RB; A streamed from global (fragment-major), 2-phase reg dbuf
#define COMPUTE_TAP(TAPV, RB)                                                      \
    do {                                                                           \
        const unsigned short* wtapf = w2f + (size_t)(wvu * 9 + (TAPV)) * 16384;    \
        short8 aA[4], aB[4];                                                       \
        _Pragma("unroll")                                                          \
        for (int fr = 0; fr < 4; ++fr)                                             \
            aA[fr] = *reinterpret_cast<const short8*>(wtapf + fr * 512 + (l << 3));\
        _Pragma("unroll")                                                          \
        for (int fr = 0; fr < 4; ++fr)                                             \
            aB[fr] = *reinterpret_cast<const short8*>(wtapf + (4 + fr) * 512 + (l << 3)); \
        _Pragma("unroll")                                                          \
        for (int s = 0; s < 8; ++s) {                                              \
            short8 aC[4];                                                          \
            if (s < 6) {                                                           \
                _Pragma("unroll")                                                  \
                for (int fr = 0; fr < 4; ++fr)                                     \
                    aC[fr] = *reinterpret_cast<const short8*>(                     \
                        wtapf + (size_t)((s + 2) * 4 + fr) * 512 + (l << 3));      \
            }                                                                      \
            short8 b[4];                                                           \
            _Pragma("unroll")                                                      \
            for (int fc = 0; fc < 4; ++fc) {                                       \
                int prow = fc * 16 + (l & 15);                                     \
                int cg8 = (s << 2) + (l >> 4);                                     \
                b[fc] = *reinterpret_cast<const short8*>(                          \
                    (RB) + prow * 256 + ((cg8 ^ (prow & 7)) << 3));                \
            }                                                                      \
            __builtin_amdgcn_s_setprio(1);                                         \
            _Pragma("unroll")                                                      \
            for (int fr = 0; fr < 4; ++fr)                                         \
                _Pragma("unroll")                                                  \
                for (int fc = 0; fc < 4; ++fc)                                     \
                    acc[fr][fc] = __builtin_amdgcn_mfma_f32_16x16x32_bf16(         \
                        aA[fr], b[fc], acc[fr][fc], 0, 0, 0);                      \
            __builtin_amdgcn_s_setprio(0);                                         \
            if (s < 7) {                                                           \
                _Pragma("unroll")                                                  \
                for (int fr = 0; fr < 4; ++fr) { aA[fr] = aB[fr]; aB[fr] = aC[fr]; } \
            }                                                                      \
        }                                                                          \
    } while (0)

    STAGE_B(0, Bs[0]);
    __syncthreads();
#pragma unroll 1
    for (int it = 0; it < 4; ++it) {
        int tap = it * 2;
        COMPUTE_TAP(tap, Bs[0]);
        STAGE_B(tap + 1, Bs[1]);
        __syncthreads();
        COMPUTE_TAP(tap + 1, Bs[1]);
        STAGE_B(tap + 2, Bs[0]);
        __syncthreads();
    }
    COMPUTE_TAP(8, Bs[0]);
#undef STAGE_B
#undef COMPUTE_TAP

    float* outp = out + (size_t)br * NPIX + (size_t)(bb * 256) * HWP + y * 64;
#pragma unroll
    for (int fr = 0; fr < 4; ++fr) {
        int o = wvu * 64 + fr * 16 + ((l >> 4) << 2);
#pragma unroll
        for (int fc = 0; fc < 4; ++fc) {
            int pxc = fc * 16 + (l & 15);
#pragma unroll
            for (int reg = 0; reg < 4; ++reg) {
                float v = acc[fr][fc][reg] + bias[o + reg];
                ntst_f(&outp[(size_t)(o + reg) * HWP + pxc], fmaxf(v, 0.f));
            }
        }
    }
}

// ---------------- tier-B sample2 + gemm2 ----------------
__launch_bounds__(256)
__global__ void sample2_kernel(const unsigned short* __restrict__ ht, const float* __restrict__ off,
                               unsigned short* __restrict__ sm, int b0) {
    int y   = blockIdx.x;
    int tap = blockIdx.y;
    int bb  = b0 + blockIdx.z;
    int t   = threadIdx.x;
    int lane = t & 63;
    int wv  = t >> 6;
    int ky = tap / 3, kx = tap % 3;
    const unsigned short* htb = ht + (size_t)bb * HWP * 256;
    const float* offy = off + ((bb * 18 + 2 * tap) * 64 + y) * 64;
    const float* offx = off + ((bb * 18 + 2 * tap + 1) * 64 + y) * 64;
    int mrow = ((bb - b0) * 64 + y) * 64;
#pragma unroll 4
    for (int i = 0; i < 16; ++i) {
        int px = wv * 16 + i;
        float dy = offy[px];
        float dx = offx[px];
        float sy = (float)(y - 1 + ky) + dy;
        float sx = (float)(px - 1 + kx) + dx;
        float y0f = floorf(sy), x0f = floorf(sx);
        float ty = sy - y0f, tx = sx - x0f;
        int iy0 = (int)y0f, ix0 = (int)x0f;
        int iy1 = iy0 + 1, ix1 = ix0 + 1;
        bool vy0 = (iy0 >= 0) & (iy0 < 64);
        bool vy1 = (iy1 >= 0) & (iy1 < 64);
        bool vx0 = (ix0 >= 0) & (ix0 < 64);
        bool vx1 = (ix1 >= 0) & (ix1 < 64);
        int cy0 = min(max(iy0, 0), 63), cy1 = min(max(iy1, 0), 63);
        int cx0 = min(max(ix0, 0), 63), cx1 = min(max(ix1, 0), 63);
        float w00 = (1.f - ty) * (1.f - tx) * ((vy0 & vx0) ? 1.f : 0.f);
        float w01 = (1.f - ty) * tx * ((vy0 & vx1) ? 1.f : 0.f);
        float w10 = ty * (1.f - tx) * ((vy1 & vx0) ? 1.f : 0.f);
        float w11 = ty * tx * ((vy1 & vx1) ? 1.f : 0.f);
        int le = lane << 2;
        bf16x4 q00 = *reinterpret_cast<const bf16x4*>(htb + ((cy0 * 64 + cx0) << 8) + le);
        bf16x4 q01 = *reinterpret_cast<const bf16x4*>(htb + ((cy0 * 64 + cx1) << 8) + le);
        bf16x4 q10 = *reinterpret_cast<const bf16x4*>(htb + ((cy1 * 64 + cx0) << 8) + le);
        bf16x4 q11 = *reinterpret_cast<const bf16x4*>(htb + ((cy1 * 64 + cx1) << 8) + le);
        f32x4 s;
#pragma unroll
        for (int j = 0; j < 4; ++j)
            s[j] = fmaf(w00, bf2f(q00[j]),
                   fmaf(w01, bf2f(q01[j]),
                   fmaf(w10, bf2f(q10[j]), w11 * bf2f(q11[j]))));
        uint2 pk;
        pk.x = cvt_pk_bf16(s[0], s[1]);
        pk.y = cvt_pk_bf16(s[2], s[3]);
        *reinterpret_cast<uint2*>(sm + (size_t)(mrow + px) * KDIM + tap * 256 + lane * 4) = pk;
    }
}

__launch_bounds__(256)
__global__ void gemm2_kernel(const unsigned short* __restrict__ w2b,
                             const unsigned short* __restrict__ smb, size_t smstride,
                             const float* __restrict__ tb0, const float* __restrict__ tb1,
                             float* __restrict__ out, int mbase) {
    __shared__ unsigned short As[128 * 64];
    __shared__ unsigned short Bs[64 * 64];
    int mt = blockIdx.x;
    int ot = blockIdx.y;
    int br = blockIdx.z;
    const unsigned short* w2 = w2b + (size_t)br * 589824;
    const unsigned short* sm = smb + (size_t)br * smstride;
    const float* bias = br ? tb1 : tb0;
    float* outp = out + (size_t)br * NPIX;
    int t  = threadIdx.x;
    int l  = t & 63;
    int w  = t >> 6;
    int wr = w >> 1, wc = w & 1;
    int o0 = ot * 128, m0 = mt * 64;
    f32x4 acc[4][2];
#pragma unroll
    for (int i = 0; i < 4; ++i)
#pragma unroll
        for (int j = 0; j < 2; ++j) acc[i][j] = (f32x4){0.f, 0.f, 0.f, 0.f};

    for (int ks = 0; ks < KDIM / 64; ++ks) {
        int k0 = ks * 64;
#pragma unroll
        for (int rA = 0; rA < 4; ++rA) {
            int s = rA * 256 + t;
            int row = s >> 3, cg = (s & 7) ^ (row & 7);
            gload_lds16(w2 + (size_t)(o0 + row) * KDIM + k0 + cg * 8, As + s * 8);
        }
#pragma unroll
        for (int rB = 0; rB < 2; ++rB) {
            int s = rB * 256 + t;
            int row = s >> 3, cg = (s & 7) ^ (row & 7);
            gload_lds16(sm + (size_t)(m0 + row) * KDIM + k0 + cg * 8, Bs + s * 8);
        }
        __syncthreads();
#pragma unroll
        for (int half = 0; half < 2; ++half) {
            short8 a[4], b[2];
#pragma unroll
            for (int fr = 0; fr < 4; ++fr) {
                int row = wr * 64 + fr * 16 + (l & 15);
                int oct = half * 4 + (l >> 4);
                a[fr] = *reinterpret_cast<const short8*>(As + row * 64 + ((oct ^ (row & 7)) * 8));
            }
#pragma unroll
            for (int fc = 0; fc < 2; ++fc) {
                int row = wc * 32 + fc * 16 + (l & 15);
                int oct = half * 4 + (l >> 4);
                b[fc] = *reinterpret_cast<const short8*>(Bs + row * 64 + ((oct ^ (row & 7)) * 8));
            }
#pragma unroll
            for (int fr = 0; fr < 4; ++fr)
#pragma unroll
                for (int fc = 0; fc < 2; ++fc)
                    acc[fr][fc] = __builtin_amdgcn_mfma_f32_16x16x32_bf16(a[fr], b[fc], acc[fr][fc], 0, 0, 0);
        }
        __syncthreads();
    }

#pragma unroll
    for (int fr = 0; fr < 4; ++fr) {
        int o = o0 + wr * 64 + fr * 16 + ((l >> 4) << 2);
#pragma unroll
        for (int fc = 0; fc < 2; ++fc) {
            int mg = mbase + m0 + wc * 32 + fc * 16 + (l & 15);
            int bbv = mg >> 12;
            int pix = mg & 4095;
            float* op = outp + (size_t)(bbv * 256) * HWP + pix;
#pragma unroll
            for (int reg = 0; reg < 4; ++reg) {
                float v = acc[fr][fc][reg] + bias[o + reg];
                op[(size_t)(o + reg) * HWP] = fmaxf(v, 0.f);
            }
        }
    }
}

extern "C" void kernel_launch(void* const* d_in, const int* in_sizes, int n_in,
                              void* d_out, int out_size, void* d_ws, size_t ws_size,
                              hipStream_t stream) {
    const float* feat = (const float*)d_in[0];
    char* base = (char*)d_ws;
    float* outp = (float*)d_out;
    const size_t perb = (size_t)HWP * KDIM * 2;                 // 18,874,368

    const float* dw0 = (const float*)d_in[1];
    const float* db0 = (const float*)d_in[2];
    const float* ow0 = (const float*)d_in[3];
    const float* ob0 = (const float*)d_in[4];
    const float* tw0 = (const float*)d_in[5];
    const float* tb0 = (const float*)d_in[6];
    const float* dw1 = (const float*)d_in[7];
    const float* db1 = (const float*)d_in[8];
    const float* ow1 = (const float*)d_in[9];
    const float* ob1 = (const float*)d_in[10];
    const float* tw1 = (const float*)d_in[11];
    const float* tb1 = (const float*)d_in[12];

    // ---- Tier A layout ----
    // ht2[2]  0 .. 33,554,432   (bf16)
    // (gap)   33,554,432 .. 35,913,728
    // w2A[2]  35,913,728 .. 38,273,024   (fragment-major)
    // w2o[2]  38,273,024 .. 38,567,936
    // fbt     38,567,936 .. 46,956,544   (dead after gemm1x1; reused for descriptors)
    //   dwq   38,567,936 .. 43,286,528   (294912 x f32x4)
    //   dcq   43,286,528 .. 45,645,824   (294912 x u16x4)
    // w1b2[2] 46,956,544 .. 47,218,688
    bool tierA = ws_size >= 47218688;

    if (tierA) {
        unsigned short* ht2 = (unsigned short*)base;
        unsigned short* w2A = (unsigned short*)(base + 35913728);
        unsigned short* w2o = (unsigned short*)(base + 38273024);
        unsigned short* fbt = (unsigned short*)(base + 38567936);
        unsigned short* w1b2 = (unsigned short*)(base + 46956544);
        float* dwq = (float*)(base + 38567936);
        unsigned short* dcq = (unsigned short*)(base + 38567936 + 4718592);

        hipLaunchKernelGGL(prep_all_kernel, dim3(6720), dim3(256), 0, stream,
                           feat, fbt, dw0, dw1, tw0, tw1, ow0, ow1, w1b2, w2A, w2o);
        hipLaunchKernelGGL(gemm1x1_kernel, dim3(64, 2, 8), dim3(256), 0, stream,
                           w1b2, fbt, db0, db1, (float*)nullptr, ht2, 0);
        hipLaunchKernelGGL(off_mfma_kernel, dim3(512), dim3(256), 0, stream,
                           w2o, ht2, ob0, ob1, dwq, dcq);
        hipLaunchKernelGGL(dgemm_fused_kernel, dim3(512), dim3(256), 0, stream,
                           w2A, ht2, dwq, dcq, tb0, tb1, outp);
        return;
    }

    // ---- Tier B (bf16-ht sample2 + gemm2, per-branch) ----
    float* h   = (float*)base;
    float* off = h + NPIX;
    unsigned short* w2 = (unsigned short*)(base + 17956864);
    float* owt = (float*)(base + 19136512);
    unsigned short* ht = (unsigned short*)(base + 19302400);
    unsigned short* smN = (unsigned short*)(base + 27691008);
    float* partN = (float*)(base + 27691008);
    unsigned short* fbtN = (unsigned short*)(base + 27691008 + 9437184);
    unsigned short* w1bN = (unsigned short*)(base + 27691008 + 17825792);

    int nb = 0;
    if (27691008 + 4 * perb <= ws_size) nb = 4;
    else if (27691008 + 2 * perb <= ws_size) nb = 2;
    else nb = 1;

    for (int br = 0; br < 2; ++br) {
        const float* dw = (const float*)d_in[1 + 6 * br];
        const float* db = (const float*)d_in[2 + 6 * br];
        const float* ow = (const float*)d_in[3 + 6 * br];
        const float* ob = (const float*)d_in[4 + 6 * br];
        const float* tw = (const float*)d_in[5 + 6 * br];
        const float* tb = (const float*)d_in[6 + 6 * br];

        hipLaunchKernelGGL(prep_fb16_kernel, dim3(64, 4, 4), dim3(256), 0, stream, feat, fbtN);
        hipLaunchKernelGGL(prep_w12_kernel, dim3(256), dim3(256), 0, stream, dw, dw, w1bN);
        hipLaunchKernelGGL(gemm1x1_kernel, dim3(64, 2, 4), dim3(256), 0, stream,
                           w1bN, fbtN, db, db, h, ht, 1);
        hipLaunchKernelGGL(prep_ow2_kernel, dim3(162), dim3(256), 0, stream, ow, ow, owt);
        hipLaunchKernelGGL(off_conv_part_kernel, dim3(256, 8, 1), dim3(256), 0, stream,
                           h, owt, partN);
        hipLaunchKernelGGL(off_reduce2_kernel, dim3(1152), dim3(256), 0, stream,
                           partN, ob, ob, off);
        hipLaunchKernelGGL(prep_w2_kernel, dim3(2304), dim3(256), 0, stream, tw, tw, w2);

        for (int b0 = 0; b0 < 4; b0 += nb) {
            hipLaunchKernelGGL(sample2_kernel, dim3(64, 9, nb), dim3(256), 0, stream,
                               ht, off, smN, b0);
            hipLaunchKernelGGL(gemm2_kernel, dim3(nb * 64, 2, 1), dim3(256), 0, stream,
                               w2, smN, (size_t)0, tb, tb, outp + br * NPIX, b0 * HWP);
        }
    }
}

// Round 8
// 121.448 us; speedup vs baseline: 1.1099x; 1.1099x over previous
//
#include <hip/hip_runtime.h>

// Shapes: B=4, C=256, H=W=64, HW=4096, Co=256, offC=18, KK=9, K-dim = 9*256 = 2304
#define HWP 4096
#define NPIX 4194304   // B*256*4096
#define KDIM 2304

typedef __attribute__((ext_vector_type(4))) float f32x4;
typedef __attribute__((ext_vector_type(4))) int   i32x4;
typedef __attribute__((ext_vector_type(8))) short short8;
typedef __attribute__((ext_vector_type(4))) unsigned short bf16x4;
typedef __attribute__((ext_vector_type(4))) unsigned short u16x4;

__device__ __forceinline__ unsigned short bf16_rne(float f) {
    unsigned int u = __builtin_bit_cast(unsigned int, f);
    u += 0x7FFFu + ((u >> 16) & 1u);
    return (unsigned short)(u >> 16);
}

__device__ __forceinline__ float bf2f(unsigned short u) {
    return __builtin_bit_cast(float, (unsigned int)u << 16);
}

__device__ __forceinline__ float u2f_lo(unsigned int u) {
    return __builtin_bit_cast(float, u << 16);
}

__device__ __forceinline__ float u2f_hi(unsigned int u) {
    return __builtin_bit_cast(float, u & 0xFFFF0000u);
}

__device__ __forceinline__ unsigned int cvt_pk_bf16(float lo, float hi) {
    unsigned int r;
    asm("v_cvt_pk_bf16_f32 %0, %1, %2" : "=v"(r) : "v"(lo), "v"(hi));
    return r;
}

__device__ __forceinline__ void gload_lds16(const void* g, void* l) {
    __builtin_amdgcn_global_load_lds((const __attribute__((address_space(1))) void*)g,
                                     (__attribute__((address_space(3))) void*)l, 16, 0, 0);
}

// nt LOADS only — for zero-reuse read streams (descriptors). No nt stores anywhere:
// ht/out/fbt/w2A all have downstream readers or need L2 write-coalescing (R7 lesson).
__device__ __forceinline__ f32x4 ntld_f4(const float* p) {
    return __builtin_nontemporal_load(reinterpret_cast<const f32x4*>(p));
}
__device__ __forceinline__ u16x4 ntld_u4(const unsigned short* p) {
    return __builtin_nontemporal_load(reinterpret_cast<const u16x4*>(p));
}

// ============ merged prep: fbt (blocks 0..1023) + weights (blocks 1024..6719) ============
// w2A is FRAGMENT-MAJOR for direct global->register MFMA loads:
// addr = ((((cg*9 + tap)*8 + s)*4 + fr)*64 + l)*8 + e   (shorts)
// value = bf16(tw[o][ci][tap])  with  o = cg*64 + fr*16 + (l&15),  ci = s*32 + (l>>4)*8 + e
__global__ void prep_all_kernel(const float* __restrict__ x, unsigned short* __restrict__ fbt,
                                const float* __restrict__ dw0, const float* __restrict__ dw1,
                                const float* __restrict__ tw0, const float* __restrict__ tw1,
                                const float* __restrict__ ow0, const float* __restrict__ ow1,
                                unsigned short* __restrict__ w1b2,
                                unsigned short* __restrict__ w2A,
                                unsigned short* __restrict__ w2o) {
    __shared__ float T[64][65];
    int b = blockIdx.x;
    int t = threadIdx.x;
    if (b < 1024) {
        // fbt[b][pix][ci] = bf16(feat[b][ci][pix])  -- vectorized transpose:
        // read float4 (1 KB/wave-instr), write bf16x4 (512 B/wave-instr).
        int pt = b & 63, ct = (b >> 6) & 3, bb = b >> 8;
        int lane = t & 63;
        int w = t >> 6;          // wave 0..3
        int c0 = ct * 64, p0 = pt * 64;
        const float* xb = x + (size_t)(bb * 256 + c0) * HWP + p0;
#pragma unroll
        for (int j = 0; j < 4; ++j) {
            int ci = w * 16 + j * 4 + (lane >> 4);
            int px = (lane & 15) * 4;
            float4 v = *reinterpret_cast<const float4*>(xb + (size_t)ci * HWP + px);
            T[ci][px]     = v.x;
            T[ci][px + 1] = v.y;
            T[ci][px + 2] = v.z;
            T[ci][px + 3] = v.w;
        }
        __syncthreads();
        unsigned short* ob = fbt + ((size_t)bb * HWP + p0) * 256 + c0;
#pragma unroll
        for (int j = 0; j < 4; ++j) {
            int px  = w * 16 + j * 4 + (lane >> 4);
            int ci4 = (lane & 15) * 4;
            bf16x4 o4;
            o4[0] = bf16_rne(T[ci4 + 0][px]);
            o4[1] = bf16_rne(T[ci4 + 1][px]);
            o4[2] = bf16_rne(T[ci4 + 2][px]);
            o4[3] = bf16_rne(T[ci4 + 3][px]);
            *reinterpret_cast<bf16x4*>(ob + (size_t)px * 256 + ci4) = o4;
        }
        return;
    }
    int idx = (b - 1024) * 256 + t;   // up to 5696*256
    if (idx < 131072) {
        int br = idx >> 16;
        int i  = idx & 65535;
        const float* dw = br ? dw1 : dw0;
        w1b2[idx] = bf16_rne(dw[i]);
    } else if (idx < 131072 + 1179648) {
        int j = idx - 131072;
        int br = j >= 589824;
        int i  = br ? j - 589824 : j;
        const float* tw = br ? tw1 : tw0;
        int cg = i / 147456;            // 147456 = 9*8*4*64*8
        int r  = i - cg * 147456;
        int tap = r >> 14;              // / 16384
        int r2 = r & 16383;
        int s  = r2 >> 11;
        int fr = (r2 >> 9) & 3;
        int l  = (r2 >> 3) & 63;
        int e  = r2 & 7;
        int o  = cg * 64 + fr * 16 + (l & 15);
        int ci = s * 32 + ((l >> 4) << 3) + e;
        w2A[j] = bf16_rne(tw[(o * 256 + ci) * 9 + tap]);
    } else {
        int j = idx - 131072 - 1179648;   // < 147456
        int br = j >= 73728;
        int i  = br ? j - 73728 : j;
        const float* ow = br ? ow1 : ow0;
        int m = i / 2304;
        int k = i - m * 2304;
        int tap = k >> 8;
        int ci  = k & 255;
        w2o[j] = (m < 18) ? bf16_rne(ow[(m * 256 + ci) * 9 + tap]) : (unsigned short)0;
    }
}

// ---------------- tier-B small preps ----------------
__global__ void prep_w2_kernel(const float* __restrict__ tw0, const float* __restrict__ tw1,
                               unsigned short* __restrict__ w2) {
    int idx = blockIdx.x * 256 + threadIdx.x;
    int br = idx >= 589824;
    int i  = br ? idx - 589824 : idx;
    const float* tw = br ? tw1 : tw0;
    int ci = i & 255;
    int r  = i >> 8;
    int tap = r % 9;
    int o   = r / 9;
    w2[idx] = bf16_rne(tw[(o * 256 + ci) * 9 + tap]);
}

__global__ void prep_ow2_kernel(const float* __restrict__ ow0, const float* __restrict__ ow1,
                                float* __restrict__ owt) {
    int idx = blockIdx.x * 256 + threadIdx.x;
    int br = idx >= 41472;
    int i  = br ? idx - 41472 : idx;
    const float* ow = br ? ow1 : ow0;
    int co = i % 18;
    int r  = i / 18;
    int k  = r % 9;
    int ci = r / 9;
    owt[idx] = ow[(co * 256 + ci) * 9 + k];
}

__global__ void prep_w12_kernel(const float* __restrict__ dw0, const float* __restrict__ dw1,
                                unsigned short* __restrict__ w1b) {
    int idx = blockIdx.x * 256 + threadIdx.x;
    int br = idx >> 16;
    int i  = idx & 65535;
    const float* dw = br ? dw1 : dw0;
    w1b[idx] = bf16_rne(dw[i]);
}

__global__ void prep_fb16_kernel(const float* __restrict__ x, unsigned short* __restrict__ fbt) {
    __shared__ float T[64][65];
    int pt = blockIdx.x;
    int ct = blockIdx.y;
    int bb = blockIdx.z;
    int t = threadIdx.x;
    int lane = t & 63;
    int r = t >> 6;
    int c0 = ct * 64, p0 = pt * 64;
    const float* xb = x + (size_t)(bb * 256 + c0) * HWP + p0;
#pragma unroll
    for (int rr = 0; rr < 16; ++rr) {
        int ci = r * 16 + rr;
        T[ci][lane] = xb[(size_t)ci * HWP + lane];
    }
    __syncthreads();
    unsigned short* ob = fbt + ((size_t)bb * HWP + p0) * 256 + c0;
#pragma unroll
    for (int rr = 0; rr < 16; ++rr) {
        int px = r * 16 + rr;
        ob[(size_t)px * 256 + lane] = bf16_rne(T[lane][px]);
    }
}

// ------- conv1x1 MFMA GEMM; z = br*4+bb; writes ht (bf16) and optionally h (fp32) -------
__launch_bounds__(256)
__global__ void gemm1x1_kernel(const unsigned short* __restrict__ w1b2,
                               const unsigned short* __restrict__ fbt,
                               const float* __restrict__ db0, const float* __restrict__ db1,
                               float* __restrict__ h2, unsigned short* __restrict__ ht2,
                               int write_h) {
    __shared__ unsigned short As[128 * 64];
    __shared__ unsigned short Bs[64 * 64];
    int pt = blockIdx.x;
    int ot = blockIdx.y;
    int z  = blockIdx.z;
    int bb = z & 3;
    int br = z >> 2;
    const unsigned short* w1b = w1b2 + (size_t)br * 65536;
    const float* db = br ? db1 : db0;
    int t  = threadIdx.x;
    int l  = t & 63;
    int w  = t >> 6;
    int wr = w >> 1, wc = w & 1;
    int o0 = ot * 128, p0 = pt * 64;
    const unsigned short* fb = fbt + (size_t)bb * HWP * 256;
    f32x4 acc[4][2];
#pragma unroll
    for (int i = 0; i < 4; ++i)
#pragma unroll
        for (int j = 0; j < 2; ++j) acc[i][j] = (f32x4){0.f, 0.f, 0.f, 0.f};

    for (int ks = 0; ks < 4; ++ks) {
        int k0 = ks * 64;
#pragma unroll
        for (int rA = 0; rA < 4; ++rA) {
            int s = rA * 256 + t;
            int row = s >> 3, cg = (s & 7) ^ (row & 7);
            gload_lds16(w1b + (size_t)(o0 + row) * 256 + k0 + cg * 8, As + s * 8);
        }
#pragma unroll
        for (int rB = 0; rB < 2; ++rB) {
            int s = rB * 256 + t;
            int row = s >> 3, cg = (s & 7) ^ (row & 7);
            gload_lds16(fb + (size_t)(p0 + row) * 256 + k0 + cg * 8, Bs + s * 8);
        }
        __syncthreads();
#pragma unroll
        for (int half = 0; half < 2; ++half) {
            short8 a[4], b[2];
#pragma unroll
            for (int fr = 0; fr < 4; ++fr) {
                int row = wr * 64 + fr * 16 + (l & 15);
                int oct = half * 4 + (l >> 4);
                a[fr] = *reinterpret_cast<const short8*>(As + row * 64 + ((oct ^ (row & 7)) * 8));
            }
#pragma unroll
            for (int fc = 0; fc < 2; ++fc) {
                int row = wc * 32 + fc * 16 + (l & 15);
                int oct = half * 4 + (l >> 4);
                b[fc] = *reinterpret_cast<const short8*>(Bs + row * 64 + ((oct ^ (row & 7)) * 8));
            }
#pragma unroll
            for (int fr = 0; fr < 4; ++fr)
#pragma unroll
                for (int fc = 0; fc < 2; ++fc)
                    acc[fr][fc] = __builtin_amdgcn_mfma_f32_16x16x32_bf16(a[fr], b[fc], acc[fr][fc], 0, 0, 0);
        }
        __syncthreads();
    }

    float* hb = h2 + (size_t)br * NPIX + (size_t)bb * 256 * HWP;
    unsigned short* htb = ht2 + (size_t)br * NPIX + (size_t)bb * HWP * 256;
#pragma unroll
    for (int fr = 0; fr < 4; ++fr) {
        int o = o0 + wr * 64 + fr * 16 + ((l >> 4) << 2);
#pragma unroll
        for (int fc = 0; fc < 2; ++fc) {
            int p = p0 + wc * 32 + fc * 16 + (l & 15);
            f32x4 v;
#pragma unroll
            for (int reg = 0; reg < 4; ++reg) {
                v[reg] = acc[fr][fc][reg] + db[o + reg];
                if (write_h) hb[(size_t)(o + reg) * HWP + p] = v[reg];
            }
            uint2 pk;
            pk.x = cvt_pk_bf16(v[0], v[1]);
            pk.y = cvt_pk_bf16(v[2], v[3]);
            *reinterpret_cast<uint2*>(htb + (size_t)p * 256 + o) = pk;
        }
    }
}

// ---------------- offset conv3x3 as MFMA mini-GEMM (4-wave K-split) ----------------
// Epilogue emits per-(px,tap) sampling descriptors:
// 4 f32 bilinear weights (validity folded) + 4 packed u16 clamped pixel indices.
__launch_bounds__(256)
__global__ void off_mfma_kernel(const unsigned short* __restrict__ w2o,
                                const unsigned short* __restrict__ ht2,
                                const float* __restrict__ ob0, const float* __restrict__ ob1,
                                float* __restrict__ dwq, unsigned short* __restrict__ dcq) {
    __shared__ float red[4][1152];   // 18 KB
    int id = blockIdx.x;          // 512 = br*256 + bb*64 + y
    int br = id >> 8;
    int bb = (id >> 6) & 3;
    int y  = id & 63;
    const unsigned short* wA = w2o + (size_t)br * 73728;
    const unsigned short* htb = ht2 + (size_t)br * NPIX + (size_t)bb * HWP * 256;
    const float* ob = br ? ob1 : ob0;
    int t = threadIdx.x;
    int l = t & 63;
    int w = t >> 6;               // wave 0..3
    short8 zero = {};
    f32x4 acc[2][4];
#pragma unroll
    for (int i = 0; i < 2; ++i)
#pragma unroll
        for (int j = 0; j < 4; ++j) acc[i][j] = (f32x4){0.f, 0.f, 0.f, 0.f};

    for (int tap = 0; tap < 9; ++tap) {
        int ky = tap / 3, kx = tap % 3;
        int yy = y + ky - 1;
        bool vy = (yy >= 0) && (yy < 64);
        int cyy = min(max(yy, 0), 63);
#pragma unroll
        for (int sh = 0; sh < 2; ++sh) {
            int s = w * 2 + sh;   // wave-private K quarter
            short8 a[2], b[4];
#pragma unroll
            for (int fr = 0; fr < 2; ++fr)
                a[fr] = *reinterpret_cast<const short8*>(
                    wA + (size_t)(fr * 16 + (l & 15)) * KDIM + tap * 256 + s * 32 + ((l >> 4) << 3));
#pragma unroll
            for (int fc = 0; fc < 4; ++fc) {
                int px = fc * 16 + (l & 15);
                int xx = px + kx - 1;
                bool v = vy && (xx >= 0) && (xx < 64);
                int cxx = min(max(xx, 0), 63);
                short8 bv = *reinterpret_cast<const short8*>(
                    htb + (size_t)(cyy * 64 + cxx) * 256 + s * 32 + ((l >> 4) << 3));
                b[fc] = v ? bv : zero;
            }
#pragma unroll
            for (int fr = 0; fr < 2; ++fr)
#pragma unroll
                for (int fc = 0; fc < 4; ++fc)
                    acc[fr][fc] = __builtin_amdgcn_mfma_f32_16x16x32_bf16(a[fr], b[fc], acc[fr][fc], 0, 0, 0);
        }
    }

    // partials -> LDS, reduce over 4 waves
#pragma unroll
    for (int fr = 0; fr < 2; ++fr)
#pragma unroll
        for (int fc = 0; fc < 4; ++fc) {
            int px = fc * 16 + (l & 15);
#pragma unroll
            for (int reg = 0; reg < 4; ++reg) {
                int co = fr * 16 + ((l >> 4) << 2) + reg;
                if (co < 18) red[w][co * 64 + px] = acc[fr][fc][reg];
            }
        }
    __syncthreads();

    // descriptor epilogue: 64 px x 9 taps for this (br,bb,y)
    size_t dbase = ((size_t)(br * 4 + bb) * 9) * 4096 + (size_t)(y * 64);
    for (int e = t; e < 576; e += 256) {
        int tap = e >> 6, px = e & 63;
        int c0 = 2 * tap, c1 = 2 * tap + 1;
        float dy = ob[c0] + red[0][c0 * 64 + px] + red[1][c0 * 64 + px]
                          + red[2][c0 * 64 + px] + red[3][c0 * 64 + px];
        float dx = ob[c1] + red[0][c1 * 64 + px] + red[1][c1 * 64 + px]
                          + red[2][c1 * 64 + px] + red[3][c1 * 64 + px];
        int ky = tap / 3, kx = tap % 3;
        float sy = (float)(y - 1 + ky) + dy;
        float sx = (float)(px - 1 + kx) + dx;
        float y0f = floorf(sy), x0f = floorf(sx);
        float ty = sy - y0f, tx = sx - x0f;
        int iy0 = (int)y0f, ix0 = (int)x0f;
        int iy1 = iy0 + 1, ix1 = ix0 + 1;
        bool vy0 = (iy0 >= 0) & (iy0 < 64);
        bool vy1 = (iy1 >= 0) & (iy1 < 64);
        bool vx0 = (ix0 >= 0) & (ix0 < 64);
        bool vx1 = (ix1 >= 0) & (ix1 < 64);
        int cy0 = min(max(iy0, 0), 63), cy1 = min(max(iy1, 0), 63);
        int cx0 = min(max(ix0, 0), 63), cx1 = min(max(ix1, 0), 63);
        f32x4 ww;
        ww[0] = (1.f - ty) * (1.f - tx) * ((vy0 & vx0) ? 1.f : 0.f);
        ww[1] = (1.f - ty) * tx * ((vy0 & vx1) ? 1.f : 0.f);
        ww[2] = ty * (1.f - tx) * ((vy1 & vx0) ? 1.f : 0.f);
        ww[3] = ty * tx * ((vy1 & vx1) ? 1.f : 0.f);
        u16x4 pc;
        pc[0] = (unsigned short)(cy0 * 64 + cx0);
        pc[1] = (unsigned short)(cy0 * 64 + cx1);
        pc[2] = (unsigned short)(cy1 * 64 + cx0);
        pc[3] = (unsigned short)(cy1 * 64 + cx1);
        size_t di = dbase + (size_t)tap * 4096 + px;
        *reinterpret_cast<f32x4*>(dwq + di * 4) = ww;
        *reinterpret_cast<u16x4*>(dcq + di * 4) = pc;
    }
}

// ---------------- tier-B offset conv ----------------
__global__ void off_conv_part_kernel(const float* __restrict__ h2, const float* __restrict__ owt2,
                                     float* __restrict__ part2) {
    int y  = blockIdx.x & 63;
    int bb = blockIdx.x >> 6;
    int c  = blockIdx.y;
    int br = blockIdx.z;
    const float* h = h2 + (size_t)br * NPIX;
    const float* owt = owt2 + (size_t)br * 41472;
    float* part = part2 + (size_t)br * 2359296;
    int t  = threadIdx.x;
    int x  = t & 63;
    int wv = __builtin_amdgcn_readfirstlane(t >> 6);
    int  toff[9];
    bool tval[9];
#pragma unroll
    for (int ky = 0; ky < 3; ++ky) {
        int yy = y + ky - 1;
        bool vy = (yy >= 0) && (yy < 64);
        int cyy = min(max(yy, 0), 63);
#pragma unroll
        for (int kx = 0; kx < 3; ++kx) {
            int xx = x + kx - 1;
            tval[ky * 3 + kx] = vy && (xx >= 0) && (xx < 64);
            toff[ky * 3 + kx] = cyy * 64 + min(max(xx, 0), 63);
        }
    }
    float acc[18];
#pragma unroll
    for (int co = 0; co < 18; ++co) acc[co] = 0.f;
    int ci0 = c * 32 + wv * 8;
    const float* hb = h + (size_t)(bb * 256 + ci0) * HWP;
#pragma unroll
    for (int i = 0; i < 8; ++i) {
        const float* hc = hb + i * HWP;
        const float* wci = owt + (size_t)(ci0 + i) * 162;
#pragma unroll
        for (int k = 0; k < 9; ++k) {
            float hv = hc[toff[k]];
            hv = tval[k] ? hv : 0.f;
            const float* wk = wci + k * 18;
#pragma unroll
            for (int co = 0; co < 18; ++co)
                acc[co] = fmaf(wk[co], hv, acc[co]);
        }
    }
    __shared__ float red[4][18][64];
    int wvl = t >> 6;
#pragma unroll
    for (int co = 0; co < 18; ++co) red[wvl][co][x] = acc[co];
    __syncthreads();
    if (wvl == 0) {
#pragma unroll
        for (int co = 0; co < 18; ++co) {
            float s = red[0][co][x] + red[1][co][x] + red[2][co][x] + red[3][co][x];
            part[(size_t)c * 294912 + ((bb * 18 + co) << 12) + (y << 6) + x] = s;
        }
    }
}

__global__ void off_reduce2_kernel(const float* __restrict__ part2,
                                   const float* __restrict__ ob0, const float* __restrict__ ob1,
                                   float* __restrict__ off2) {
    int idx = blockIdx.x * 256 + threadIdx.x;
    int br = idx >= 294912;
    int i  = br ? idx - 294912 : idx;
    const float* part = part2 + (size_t)br * 2359296;
    const float* b = br ? ob1 : ob0;
    int co = (i >> 12) % 18;
    float s = b[co];
#pragma unroll
    for (int c = 0; c < 8; ++c) s += part[(size_t)c * 294912 + i];
    off2[idx] = s;
}

// ---------------- FUSED deform sample + GEMM + bias + ReLU ----------------
// v13 = round-6 best (v7 structure) + nt LOADS on descriptor stream only.
// 4 waves x (64 out-ch x 64 px), A direct global->reg (fragment-major w2A),
// Bs double-buffered, ONE barrier per tap.
__launch_bounds__(256, 2)
__global__ void dgemm_fused_kernel(const unsigned short* __restrict__ w2b,
                                   const unsigned short* __restrict__ ht2,
                                   const float* __restrict__ dwq,
                                   const unsigned short* __restrict__ dcq,
                                   const float* __restrict__ tb0,
                                   const float* __restrict__ tb1,
                                   float* __restrict__ out) {
    __shared__ unsigned short Bs[2][64 * 256];   // 64 KB
    int id = blockIdx.x;
    int sw = (id & 7) * 64 + (id >> 3);        // XCD swizzle
    int br = sw >> 8;
    int mt = sw & 255;
    int bb = mt >> 6;
    int y  = mt & 63;
    const unsigned short* w2f = w2b + (size_t)br * 589824;
    const unsigned short* htb = ht2 + (size_t)br * NPIX + (size_t)bb * HWP * 256;
    const float* bias = br ? tb1 : tb0;
    size_t dbase = ((size_t)(br * 4 + bb) * 9) * 4096 + (size_t)(y * 64);
    int t = threadIdx.x;
    int l = t & 63;
    int w = t >> 6;
    int wvu = __builtin_amdgcn_readfirstlane(w);
    int le = l << 2;

    f32x4 acc[4][4];
#pragma unroll
    for (int i = 0; i < 4; ++i)
#pragma unroll
        for (int j = 0; j < 4; ++j) acc[i][j] = (f32x4){0.f, 0.f, 0.f, 0.f};

// stage 16 px of tap TAPV into WB (per-wave px block)
#define STAGE_B(TAPV, WB)                                                          \
    do {                                                                           \
        const float* dwt = dwq + (dbase + (size_t)(TAPV) * 4096) * 4;              \
        const unsigned short* dct = dcq + (dbase + (size_t)(TAPV) * 4096) * 4;     \
        _Pragma("unroll")                                                          \
        for (int i_ = 0; i_ < 16; ++i_) {                                          \
            int px = wvu * 16 + i_;                                                \
            f32x4 ww = ntld_f4(dwt + (size_t)px * 4);                              \
            u16x4 pc = ntld_u4(dct + (size_t)px * 4);                              \
            int b00 = ((int)pc[0] << 8) + le;                                      \
            int b01 = ((int)pc[1] << 8) + le;                                      \
            int b10 = ((int)pc[2] << 8) + le;                                      \
            int b11 = ((int)pc[3] << 8) + le;                                      \
            uint2 u00 = *reinterpret_cast<const uint2*>(htb + b00);                \
            uint2 u01 = *reinterpret_cast<const uint2*>(htb + b01);                \
            uint2 u10 = *reinterpret_cast<const uint2*>(htb + b10);                \
            uint2 u11 = *reinterpret_cast<const uint2*>(htb + b11);                \
            float s0 = fmaf(ww[0], u2f_lo(u00.x),                                  \
                       fmaf(ww[1], u2f_lo(u01.x),                                  \
                       fmaf(ww[2], u2f_lo(u10.x), ww[3] * u2f_lo(u11.x))));        \
            float s1 = fmaf(ww[0], u2f_hi(u00.x),                                  \
                       fmaf(ww[1], u2f_hi(u01.x),                                  \
                       fmaf(ww[2], u2f_hi(u10.x), ww[3] * u2f_hi(u11.x))));        \
            float s2 = fmaf(ww[0], u2f_lo(u00.y),                                  \
                       fmaf(ww[1], u2f_lo(u01.y),                                  \
                       fmaf(ww[2], u2f_lo(u10.y), ww[3] * u2f_lo(u11.y))));        \
            float s3 = fmaf(ww[0], u2f_hi(u00.y),                                  \
                       fmaf(ww[1], u2f_hi(u01.y),                                  \
                       fmaf(ww[2], u2f_hi(u10.y), ww[3] * u2f_hi(u11.y))));        \
            uint2 pk;                                                              \
            pk.x = cvt_pk_bf16(s0, s1);                                            \
            pk.y = cvt_pk_bf16(s2, s3);                                            \
            int g = l >> 1, sub = l & 1;                                           \
            *reinterpret_cast<uint2*>((WB) + px * 256 +                            \
                (((g ^ (px & 7)) << 3) | (sub << 2))) = pk;                        \
        }                                                                          \
    } while (0)

// compute tap TAPV from RB; A streamed from global (fragment-major), 2-phase reg dbuf
#define COMPUTE_TAP(TAPV, RB)                                                      \
    do {                                                                           \
        const unsigned short* wtapf = w2f + (size_t)(wvu * 9 + (TAPV)) * 16384;    \
        short8 aA[4], aB[4];                                                       \
        _Pragma("unroll")                                                          \
        for (int fr = 0; fr < 4; ++fr)                                             \
            aA[fr] = *reinterpret_cast<const short8*>(wtapf + fr * 512 + (l << 3));\
        _Pragma("unroll")                                                          \
        for (int fr = 0; fr < 4; ++fr)                                             \
            aB[fr] = *reinterpret_cast<const short8*>(wtapf + (4 + fr) * 512 + (l << 3)); \
        _Pragma("unroll")                                                          \
        for (int s = 0; s < 8; ++s) {                                              \
            short8 aC[4];                                                          \
            if (s < 6) {                                                           \
                _Pragma("unroll")                                                  \
                for (int fr = 0; fr < 4; ++fr)                                     \
                    aC[fr] = *reinterpret_cast<const short8*>(                     \
                        wtapf + (size_t)((s + 2) * 4 + fr) * 512 + (l << 3));      \
            }                                                                      \
            short8 b[4];                                                           \
            _Pragma("unroll")                                                      \
            for (int fc = 0; fc < 4; ++fc) {                                       \
                int prow = fc * 16 + (l & 15);                                     \
                int cg8 = (s << 2) + (l >> 4);                                     \
                b[fc] = *reinterpret_cast<const short8*>(                          \
                    (RB) + prow * 256 + ((cg8 ^ (prow & 7)) << 3));                \
            }                                                                      \
            __builtin_amdgcn_s_setprio(1);                                         \
            _Pragma("unroll")                                                      \
            for (int fr = 0; fr < 4; ++fr)                                         \
                _Pragma("unroll")                                                  \
                for (int fc = 0; fc < 4; ++fc)                                     \
                    acc[fr][fc] = __builtin_amdgcn_mfma_f32_16x16x32_bf16(         \
                        aA[fr], b[fc], acc[fr][fc], 0, 0, 0);                      \
            __builtin_amdgcn_s_setprio(0);                                         \
            if (s < 7) {                                                           \
                _Pragma("unroll")                                                  \
                for (int fr = 0; fr < 4; ++fr) { aA[fr] = aB[fr]; aB[fr] = aC[fr]; } \
            }                                                                      \
        }                                                                          \
    } while (0)

    STAGE_B(0, Bs[0]);
    __syncthreads();
#pragma unroll 1
    for (int it = 0; it < 4; ++it) {
        int tap = it * 2;
        COMPUTE_TAP(tap, Bs[0]);
        STAGE_B(tap + 1, Bs[1]);
        __syncthreads();
        COMPUTE_TAP(tap + 1, Bs[1]);
        STAGE_B(tap + 2, Bs[0]);
        __syncthreads();
    }
    COMPUTE_TAP(8, Bs[0]);
#undef STAGE_B
#undef COMPUTE_TAP

    float* outp = out + (size_t)br * NPIX + (size_t)(bb * 256) * HWP + y * 64;
#pragma unroll
    for (int fr = 0; fr < 4; ++fr) {
        int o = wvu * 64 + fr * 16 + ((l >> 4) << 2);
#pragma unroll
        for (int fc = 0; fc < 4; ++fc) {
            int pxc = fc * 16 + (l & 15);
#pragma unroll
            for (int reg = 0; reg < 4; ++reg) {
                float v = acc[fr][fc][reg] + bias[o + reg];
                outp[(size_t)(o + reg) * HWP + pxc] = fmaxf(v, 0.f);
            }
        }
    }
}

// ---------------- tier-B sample2 + gemm2 ----------------
__launch_bounds__(256)
__global__ void sample2_kernel(const unsigned short* __restrict__ ht, const float* __restrict__ off,
                               unsigned short* __restrict__ sm, int b0) {
    int y   = blockIdx.x;
    int tap = blockIdx.y;
    int bb  = b0 + blockIdx.z;
    int t   = threadIdx.x;
    int lane = t & 63;
    int wv  = t >> 6;
    int ky = tap / 3, kx = tap % 3;
    const unsigned short* htb = ht + (size_t)bb * HWP * 256;
    const float* offy = off + ((bb * 18 + 2 * tap) * 64 + y) * 64;
    const float* offx = off + ((bb * 18 + 2 * tap + 1) * 64 + y) * 64;
    int mrow = ((bb - b0) * 64 + y) * 64;
#pragma unroll 4
    for (int i = 0; i < 16; ++i) {
        int px = wv * 16 + i;
        float dy = offy[px];
        float dx = offx[px];
        float sy = (float)(y - 1 + ky) + dy;
        float sx = (float)(px - 1 + kx) + dx;
        float y0f = floorf(sy), x0f = floorf(sx);
        float ty = sy - y0f, tx = sx - x0f;
        int iy0 = (int)y0f, ix0 = (int)x0f;
        int iy1 = iy0 + 1, ix1 = ix0 + 1;
        bool vy0 = (iy0 >= 0) & (iy0 < 64);
        bool vy1 = (iy1 >= 0) & (iy1 < 64);
        bool vx0 = (ix0 >= 0) & (ix0 < 64);
        bool vx1 = (ix1 >= 0) & (ix1 < 64);
        int cy0 = min(max(iy0, 0), 63), cy1 = min(max(iy1, 0), 63);
        int cx0 = min(max(ix0, 0), 63), cx1 = min(max(ix1, 0), 63);
        float w00 = (1.f - ty) * (1.f - tx) * ((vy0 & vx0) ? 1.f : 0.f);
        float w01 = (1.f - ty) * tx * ((vy0 & vx1) ? 1.f : 0.f);
        float w10 = ty * (1.f - tx) * ((vy1 & vx0) ? 1.f : 0.f);
        float w11 = ty * tx * ((vy1 & vx1) ? 1.f : 0.f);
        int le = lane << 2;
        bf16x4 q00 = *reinterpret_cast<const bf16x4*>(htb + ((cy0 * 64 + cx0) << 8) + le);
        bf16x4 q01 = *reinterpret_cast<const bf16x4*>(htb + ((cy0 * 64 + cx1) << 8) + le);
        bf16x4 q10 = *reinterpret_cast<const bf16x4*>(htb + ((cy1 * 64 + cx0) << 8) + le);
        bf16x4 q11 = *reinterpret_cast<const bf16x4*>(htb + ((cy1 * 64 + cx1) << 8) + le);
        f32x4 s;
#pragma unroll
        for (int j = 0; j < 4; ++j)
            s[j] = fmaf(w00, bf2f(q00[j]),
                   fmaf(w01, bf2f(q01[j]),
                   fmaf(w10, bf2f(q10[j]), w11 * bf2f(q11[j]))));
        uint2 pk;
        pk.x = cvt_pk_bf16(s[0], s[1]);
        pk.y = cvt_pk_bf16(s[2], s[3]);
        *reinterpret_cast<uint2*>(sm + (size_t)(mrow + px) * KDIM + tap * 256 + lane * 4) = pk;
    }
}

__launch_bounds__(256)
__global__ void gemm2_kernel(const unsigned short* __restrict__ w2b,
                             const unsigned short* __restrict__ smb, size_t smstride,
                             const float* __restrict__ tb0, const float* __restrict__ tb1,
                             float* __restrict__ out, int mbase) {
    __shared__ unsigned short As[128 * 64];
    __shared__ unsigned short Bs[64 * 64];
    int mt = blockIdx.x;
    int ot = blockIdx.y;
    int br = blockIdx.z;
    const unsigned short* w2 = w2b + (size_t)br * 589824;
    const unsigned short* sm = smb + (size_t)br * smstride;
    const float* bias = br ? tb1 : tb0;
    float* outp = out + (size_t)br * NPIX;
    int t  = threadIdx.x;
    int l  = t & 63;
    int w  = t >> 6;
    int wr = w >> 1, wc = w & 1;
    int o0 = ot * 128, m0 = mt * 64;
    f32x4 acc[4][2];
#pragma unroll
    for (int i = 0; i < 4; ++i)
#pragma unroll
        for (int j = 0; j < 2; ++j) acc[i][j] = (f32x4){0.f, 0.f, 0.f, 0.f};

    for (int ks = 0; ks < KDIM / 64; ++ks) {
        int k0 = ks * 64;
#pragma unroll
        for (int rA = 0; rA < 4; ++rA) {
            int s = rA * 256 + t;
            int row = s >> 3, cg = (s & 7) ^ (row & 7);
            gload_lds16(w2 + (size_t)(o0 + row) * KDIM + k0 + cg * 8, As + s * 8);
        }
#pragma unroll
        for (int rB = 0; rB < 2; ++rB) {
            int s = rB * 256 + t;
            int row = s >> 3, cg = (s & 7) ^ (row & 7);
            gload_lds16(sm + (size_t)(m0 + row) * KDIM + k0 + cg * 8, Bs + s * 8);
        }
        __syncthreads();
#pragma unroll
        for (int half = 0; half < 2; ++half) {
            short8 a[4], b[2];
#pragma unroll
            for (int fr = 0; fr < 4; ++fr) {
                int row = wr * 64 + fr * 16 + (l & 15);
                int oct = half * 4 + (l >> 4);
                a[fr] = *reinterpret_cast<const short8*>(As + row * 64 + ((oct ^ (row & 7)) * 8));
            }
#pragma unroll
            for (int fc = 0; fc < 2; ++fc) {
                int row = wc * 32 + fc * 16 + (l & 15);
                int oct = half * 4 + (l >> 4);
                b[fc] = *reinterpret_cast<const short8*>(Bs + row * 64 + ((oct ^ (row & 7)) * 8));
            }
#pragma unroll
            for (int fr = 0; fr < 4; ++fr)
#pragma unroll
                for (int fc = 0; fc < 2; ++fc)
                    acc[fr][fc] = __builtin_amdgcn_mfma_f32_16x16x32_bf16(a[fr], b[fc], acc[fr][fc], 0, 0, 0);
        }
        __syncthreads();
    }

#pragma unroll
    for (int fr = 0; fr < 4; ++fr) {
        int o = o0 + wr * 64 + fr * 16 + ((l >> 4) << 2);
#pragma unroll
        for (int fc = 0; fc < 2; ++fc) {
            int mg = mbase + m0 + wc * 32 + fc * 16 + (l & 15);
            int bbv = mg >> 12;
            int pix = mg & 4095;
            float* op = outp + (size_t)(bbv * 256) * HWP + pix;
#pragma unroll
            for (int reg = 0; reg < 4; ++reg) {
                float v = acc[fr][fc][reg] + bias[o + reg];
                op[(size_t)(o + reg) * HWP] = fmaxf(v, 0.f);
            }
        }
    }
}

extern "C" void kernel_launch(void* const* d_in, const int* in_sizes, int n_in,
                              void* d_out, int out_size, void* d_ws, size_t ws_size,
                              hipStream_t stream) {
    const float* feat = (const float*)d_in[0];
    char* base = (char*)d_ws;
    float* outp = (float*)d_out;
    const size_t perb = (size_t)HWP * KDIM * 2;                 // 18,874,368

    const float* dw0 = (const float*)d_in[1];
    const float* db0 = (const float*)d_in[2];
    const float* ow0 = (const float*)d_in[3];
    const float* ob0 = (const float*)d_in[4];
    const float* tw0 = (const float*)d_in[5];
    const float* tb0 = (const float*)d_in[6];
    const float* dw1 = (const float*)d_in[7];
    const float* db1 = (const float*)d_in[8];
    const float* ow1 = (const float*)d_in[9];
    const float* ob1 = (const float*)d_in[10];
    const float* tw1 = (const float*)d_in[11];
    const float* tb1 = (const float*)d_in[12];

    // ---- Tier A layout ----
    // ht2[2]  0 .. 33,554,432   (bf16)
    // (gap)   33,554,432 .. 35,913,728
    // w2A[2]  35,913,728 .. 38,273,024   (fragment-major)
    // w2o[2]  38,273,024 .. 38,567,936
    // fbt     38,567,936 .. 46,956,544   (dead after gemm1x1; reused for descriptors)
    //   dwq   38,567,936 .. 43,286,528   (294912 x f32x4)
    //   dcq   43,286,528 .. 45,645,824   (294912 x u16x4)
    // w1b2[2] 46,956,544 .. 47,218,688
    bool tierA = ws_size >= 47218688;

    if (tierA) {
        unsigned short* ht2 = (unsigned short*)base;
        unsigned short* w2A = (unsigned short*)(base + 35913728);
        unsigned short* w2o = (unsigned short*)(base + 38273024);
        unsigned short* fbt = (unsigned short*)(base + 38567936);
        unsigned short* w1b2 = (unsigned short*)(base + 46956544);
        float* dwq = (float*)(base + 38567936);
        unsigned short* dcq = (unsigned short*)(base + 38567936 + 4718592);

        hipLaunchKernelGGL(prep_all_kernel, dim3(6720), dim3(256), 0, stream,
                           feat, fbt, dw0, dw1, tw0, tw1, ow0, ow1, w1b2, w2A, w2o);
        hipLaunchKernelGGL(gemm1x1_kernel, dim3(64, 2, 8), dim3(256), 0, stream,
                           w1b2, fbt, db0, db1, (float*)nullptr, ht2, 0);
        hipLaunchKernelGGL(off_mfma_kernel, dim3(512), dim3(256), 0, stream,
                           w2o, ht2, ob0, ob1, dwq, dcq);
        hipLaunchKernelGGL(dgemm_fused_kernel, dim3(512), dim3(256), 0, stream,
                           w2A, ht2, dwq, dcq, tb0, tb1, outp);
        return;
    }

    // ---- Tier B (bf16-ht sample2 + gemm2, per-branch) ----
    float* h   = (float*)base;
    float* off = h + NPIX;
    unsigned short* w2 = (unsigned short*)(base + 17956864);
    float* owt = (float*)(base + 19136512);
    unsigned short* ht = (unsigned short*)(base + 19302400);
    unsigned short* smN = (unsigned short*)(base + 27691008);
    float* partN = (float*)(base + 27691008);
    unsigned short* fbtN = (unsigned short*)(base + 27691008 + 9437184);
    unsigned short* w1bN = (unsigned short*)(base + 27691008 + 17825792);

    int nb = 0;
    if (27691008 + 4 * perb <= ws_size) nb = 4;
    else if (27691008 + 2 * perb <= ws_size) nb = 2;
    else nb = 1;

    for (int br = 0; br < 2; ++br) {
        const float* dw = (const float*)d_in[1 + 6 * br];
        const float* db = (const float*)d_in[2 + 6 * br];
        const float* ow = (const float*)d_in[3 + 6 * br];
        const float* ob = (const float*)d_in[4 + 6 * br];
        const float* tw = (const float*)d_in[5 + 6 * br];
        const float* tb = (const float*)d_in[6 + 6 * br];

        hipLaunchKernelGGL(prep_fb16_kernel, dim3(64, 4, 4), dim3(256), 0, stream, feat, fbtN);
        hipLaunchKernelGGL(prep_w12_kernel, dim3(256), dim3(256), 0, stream, dw, dw, w1bN);
        hipLaunchKernelGGL(gemm1x1_kernel, dim3(64, 2, 4), dim3(256), 0, stream,
                           w1bN, fbtN, db, db, h, ht, 1);
        hipLaunchKernelGGL(prep_ow2_kernel, dim3(162), dim3(256), 0, stream, ow, ow, owt);
        hipLaunchKernelGGL(off_conv_part_kernel, dim3(256, 8, 1), dim3(256), 0, stream,
                           h, owt, partN);
        hipLaunchKernelGGL(off_reduce2_kernel, dim3(1152), dim3(256), 0, stream,
                           partN, ob, ob, off);
        hipLaunchKernelGGL(prep_w2_kernel, dim3(2304), dim3(256), 0, stream, tw, tw, w2);

        for (int b0 = 0; b0 < 4; b0 += nb) {
            hipLaunchKernelGGL(sample2_kernel, dim3(64, 9, nb), dim3(256), 0, stream,
                               ht, off, smN, b0);
            hipLaunchKernelGGL(gemm2_kernel, dim3(nb * 64, 2, 1), dim3(256), 0, stream,
                               w2, smN, (size_t)0, tb, tb, outp + br * NPIX, b0 * HWP);
        }
    }
}